// Round 16
// baseline (94.299 us; speedup 1.0000x reference)
//
#include <hip/hip_runtime.h>

typedef unsigned short u16;
typedef float f32x4 __attribute__((ext_vector_type(4)));
typedef __bf16 bf16x8 __attribute__((ext_vector_type(8)));

#define MFMA16(a, b, c) __builtin_amdgcn_mfma_f32_16x16x32_bf16((a), (b), (c), 0, 0, 0)

#define B_ 8
#define H_ 8
#define S_ 1024

__device__ __forceinline__ u16 f2bf(float f) {
  unsigned u = __float_as_uint(f);
  return (u16)((u + 0x7fffu + ((u >> 16) & 1u)) >> 16);
}
// pack 2 f32 -> 2 bf16 in one instr (dst.lo = a, dst.hi = b)
__device__ __forceinline__ unsigned cvtpk(float a, float b) {
  unsigned r;
  asm("v_cvt_pk_bf16_f32 %0, %1, %2" : "=v"(r) : "v"(a), "v"(b));
  return r;
}
// async global->LDS, 16B per lane. LDS dest = wave-uniform base + lane*16.
__device__ __forceinline__ void gload16(const void* g, void* l) {
  __builtin_amdgcn_global_load_lds((__attribute__((address_space(1))) const void*)g,
                                   (__attribute__((address_space(3))) void*)l, 16, 0, 0);
}

// ---------------- all fp32->bf16 converts in one dispatch ----------------
__global__ void __launch_bounds__(256) convAll(const float* __restrict__ q, const float* __restrict__ k,
                                               const float* __restrict__ v, const float* __restrict__ Wq,
                                               const float* __restrict__ Wk, const float* __restrict__ Wv,
                                               const float* __restrict__ Wo, const float* __restrict__ relk,
                                               u16* __restrict__ dq, u16* __restrict__ dk, u16* __restrict__ dv,
                                               u16* __restrict__ dWq, u16* __restrict__ dWk, u16* __restrict__ dWv,
                                               u16* __restrict__ dWo, u16* __restrict__ drelk) {
  const int bid = blockIdx.x;
  const float* s; u16* d; size_t off;
  if (bid < 12288) {
    size_t i4 = (size_t)bid * 256 + threadIdx.x;   // 3*1048576 float4s
    int tsel = (int)(i4 >> 20);
    off = (i4 & 1048575) << 2;
    s = tsel == 0 ? q : (tsel == 1 ? k : v);
    d = tsel == 0 ? dq : (tsel == 1 ? dk : dv);
  } else {
    size_t i = ((size_t)(bid - 12288) * 256 + threadIdx.x) << 2;
    if (i >= 1050688) return; // 4*262144 + 33*64
    if (i < 262144)       { s = Wq; d = dWq; off = i; }
    else if (i < 524288)  { s = Wk; d = dWk; off = i - 262144; }
    else if (i < 786432)  { s = Wv; d = dWv; off = i - 524288; }
    else if (i < 1048576) { s = Wo; d = dWo; off = i - 786432; }
    else                  { s = relk; d = drelk; off = i - 1048576; }
  }
  float4 f = *(const float4*)(s + off);
  uint2 o;
  o.x = cvtpk(f.x, f.y);
  o.y = cvtpk(f.z, f.w);
  *(uint2*)(d + off) = o;
}

// ---------------- fused Q/K/V projection GEMM: 768 blocks x 512 threads, bf16 A, BK=32, dbuf ----------------
// seg 0: Q -> bf16 head-split [B,H,S,64]; seg 1: K same; seg 2: V -> transposed [B*H,64,S].
// Measured-best schedule: STAGE(next) before compute(cur), one barrier/iter; bf16 A (f32-A variants
// all measured ~43us vs ~26us for bf16-A). 4-slot XOR source swizzle, LDS linear (pair proven in gemm_out).
// XCD-chunked block swizzle keeps the 4 bn-blocks of one A row-block on the same XCD's L2.
__global__ void __launch_bounds__(512) qkv_gemm(const u16* __restrict__ Xq, const u16* __restrict__ Xk,
                                                const u16* __restrict__ Xv, const u16* __restrict__ Wqb,
                                                const u16* __restrict__ Wkb, const u16* __restrict__ Wvb,
                                                const float* __restrict__ bq, const float* __restrict__ bk,
                                                const float* __restrict__ bv, u16* __restrict__ Qh,
                                                u16* __restrict__ Kh, u16* __restrict__ Vt) {
  __shared__ u16 As2[2][128 * 32];   // 2 x 8 KB bf16 A tiles
  __shared__ u16 Bs2[2][128 * 32];   // 2 x 8 KB bf16 W tiles
  // 768 blocks, 8 XCDs, 96 per XCD (exact): XCD x gets logical work [96x, 96x+96)
  const int w = (blockIdx.x & 7) * 96 + (blockIdx.x >> 3);
  const int seg = w >> 8, bid = w & 255;
  const u16* A = seg == 0 ? Xq : (seg == 1 ? Xk : Xv);
  const u16* W = seg == 0 ? Wqb : (seg == 1 ? Wkb : Wvb);
  const float* bias = seg == 0 ? bq : (seg == 1 ? bk : bv);
  const int tid = threadIdx.x, lane = tid & 63, wid = tid >> 6;   // wid 0..7
  const int c = lane & 15, g = lane >> 4;
  const int bm = bid >> 2, bn = bid & 3;
  const int m0 = bm << 7, n0 = bn << 7;
  const int wrow = (wid & 3) << 5;    // 0/32/64/96
  const int wcol = (wid >> 2) << 6;   // 0/64

#define STAGEQ(buf, kt_) do { \
    int s0_ = wid << 6; \
    int s_ = s0_ + lane; \
    int row_ = s_ >> 2; \
    int sl_ = (s_ & 3) ^ (row_ & 3); \
    gload16((const char*)A + ((((size_t)(m0 + row_)) << 9) + (kt_)) * 2 + (sl_ << 4), \
            (char*)As2[buf] + (s0_ << 4)); \
    gload16((const char*)W + ((((size_t)(n0 + row_)) << 9) + (kt_)) * 2 + (sl_ << 4), \
            (char*)Bs2[buf] + (s0_ << 4)); \
  } while (0)

  const f32x4 ZF = {0.f, 0.f, 0.f, 0.f};
  f32x4 acc[2][4];
#pragma unroll
  for (int i = 0; i < 2; ++i)
#pragma unroll
    for (int j = 0; j < 4; ++j) acc[i][j] = ZF;

  STAGEQ(0, 0);
  __syncthreads();   // drain prologue stage

  for (int it = 0; it < 16; ++it) {
    const int cur = it & 1;
    if (it < 15) STAGEQ(cur ^ 1, (it + 1) << 5);   // prefetch next tile, hides under compute

    bf16x8 af[2], bfr[4];
#pragma unroll
    for (int rt = 0; rt < 2; ++rt) {
      int row = wrow + (rt << 4) + c;
      af[rt] = *(const bf16x8*)((const char*)As2[cur] + row * 64 + ((g ^ (row & 3)) << 4));
    }
#pragma unroll
    for (int ct = 0; ct < 4; ++ct) {
      int row = wcol + (ct << 4) + c;
      bfr[ct] = *(const bf16x8*)((const char*)Bs2[cur] + row * 64 + ((g ^ (row & 3)) << 4));
    }
#pragma unroll
    for (int rt = 0; rt < 2; ++rt)
#pragma unroll
      for (int ct = 0; ct < 4; ++ct) acc[rt][ct] = MFMA16(af[rt], bfr[ct], acc[rt][ct]);

    if (it < 15) __syncthreads();   // drains prefetch + gates buffer swap
  }

#pragma unroll
  for (int rt = 0; rt < 2; ++rt)
#pragma unroll
    for (int ct = 0; ct < 4; ++ct) {
      int n = n0 + wcol + (ct << 4) + c;
      float bv2 = bias[n];
      if (seg == 2) {
        int b2 = m0 >> 10;
        int sbase = (m0 & 1023) + wrow + (rt << 4) + (g << 2);
        int h2 = n >> 6, d2 = n & 63;
        uint2 o;
        o.x = cvtpk(acc[rt][ct][0] + bv2, acc[rt][ct][1] + bv2);
        o.y = cvtpk(acc[rt][ct][2] + bv2, acc[rt][ct][3] + bv2);
        *(uint2*)(Vt + ((((size_t)((b2 << 3) + h2) << 6) + d2) << 10) + sbase) = o;
      } else {
        u16* out = seg == 0 ? Qh : Kh;
#pragma unroll
        for (int r = 0; r < 4; ++r) {
          int m = m0 + wrow + (rt << 4) + (g << 2) + r;
          int b = m >> 10, s = m & 1023, h = n >> 6, d = n & 63;
          out[(((((size_t)(b * H_ + h)) << 10) + s) << 6) + d] = f2bf(acc[rt][ct][r] + bv2);
        }
      }
    }
#undef STAGEQ
}

// ---------------- output GEMM: 256 blocks x 512 threads, BK=32, double-buffered ----------------
__global__ void __launch_bounds__(512) gemm_out(const u16* __restrict__ A, const u16* __restrict__ W,
                                                const float* __restrict__ bias, float* __restrict__ out) {
  __shared__ u16 As2[2][128 * 32];   // 2 x 8 KB
  __shared__ u16 Bs2[2][128 * 32];   // 2 x 8 KB
  // XCD swizzle: 256 blocks, 32 per XCD (exact)
  const int wb = (blockIdx.x & 7) * 32 + (blockIdx.x >> 3);
  const int tid = threadIdx.x, lane = tid & 63, wid = tid >> 6;
  const int c = lane & 15, g = lane >> 4;
  const int bm = wb >> 2, bn = wb & 3;
  const int m0 = bm << 7, n0 = bn << 7;
  const int wrow = (wid & 3) << 5;    // 0/32/64/96
  const int wcol = (wid >> 2) << 6;   // 0/64

#define STAGEO(buf, kt_) do { \
    int s0_ = wid << 6; \
    int s_ = s0_ + lane; \
    int row_ = s_ >> 2; \
    int sl_ = (s_ & 3) ^ (row_ & 3); \
    gload16((const char*)A + ((((size_t)(m0 + row_)) << 9) + (kt_)) * 2 + (sl_ << 4), \
            (char*)As2[buf] + (s0_ << 4)); \
    gload16((const char*)W + ((((size_t)(n0 + row_)) << 9) + (kt_)) * 2 + (sl_ << 4), \
            (char*)Bs2[buf] + (s0_ << 4)); \
  } while (0)

  const f32x4 ZF = {0.f, 0.f, 0.f, 0.f};
  f32x4 acc[2][4];
#pragma unroll
  for (int i = 0; i < 2; ++i)
#pragma unroll
    for (int j = 0; j < 4; ++j) acc[i][j] = ZF;

  STAGEO(0, 0);
  __syncthreads();

  for (int it = 0; it < 16; ++it) {
    const int cur = it & 1;
    if (it < 15) STAGEO(cur ^ 1, (it + 1) << 5);

    bf16x8 af[2], bfr[4];
#pragma unroll
    for (int rt = 0; rt < 2; ++rt) {
      int row = wrow + (rt << 4) + c;
      af[rt] = *(const bf16x8*)((const char*)As2[cur] + row * 64 + ((g ^ (row & 3)) << 4));
    }
#pragma unroll
    for (int ct = 0; ct < 4; ++ct) {
      int row = wcol + (ct << 4) + c;
      bfr[ct] = *(const bf16x8*)((const char*)Bs2[cur] + row * 64 + ((g ^ (row & 3)) << 4));
    }
#pragma unroll
    for (int rt = 0; rt < 2; ++rt)
#pragma unroll
      for (int ct = 0; ct < 4; ++ct) acc[rt][ct] = MFMA16(af[rt], bfr[ct], acc[rt][ct]);

    if (it < 15) __syncthreads();
  }

#pragma unroll
  for (int rt = 0; rt < 2; ++rt)
#pragma unroll
    for (int ct = 0; ct < 4; ++ct) {
      int n = n0 + wcol + (ct << 4) + c;
      float bv = bias[n];
#pragma unroll
      for (int r = 0; r < 4; ++r) {
        int m = m0 + wrow + (rt << 4) + (g << 2) + r;
        out[(((size_t)m) << 9) + n] = acc[rt][ct][r] + bv;
      }
    }
#undef STAGEO
}

// ---------------- flash attention: round-4 structure (8 waves, 128 q, fused qrel + rel-V) ----------------
// lane (c,g) of wave wid owns q = qbase + wid*16 + c everywhere.
__global__ void __launch_bounds__(512) flash_kernel(const u16* __restrict__ Qh, const u16* __restrict__ Kh,
                                                    const u16* __restrict__ Vt, const u16* __restrict__ relkb,
                                                    const float* __restrict__ relv, u16* __restrict__ Xout) {
  __shared__ u16 Ks[2][64 * 64];
  __shared__ u16 Vs[2][64 * 64];
  __shared__ u16 Ps[128 * 64];
  __shared__ float qrelS[128 * 34];   // exp2-domain bias table; overlaid by rvT in epilogue
  __shared__ u16 Pband[128 * 32];     // unnormalized bf16 band probs; slot 0 = low bucket
  __shared__ float rv32S[64];

  const int tid = threadIdx.x, lane = tid & 63, wid = tid >> 6;
  const int c = lane & 15, g = lane >> 4;
  // XCD swizzle: 8 chunks of 64 consecutive blocks
  const int swz = ((blockIdx.x & 7) << 6) | (blockIdx.x >> 3);
  const int bh = swz >> 3, qt = swz & 7;
  const int qbase = qt << 7;
  const size_t rowbase = ((size_t)bh) << 10;
  const int qloc = (wid << 4) + c;
  const float K1 = 0.51013619f;   // (1/sqrt(8)) * log2(e)
  const float C0 = 24.0f;

  // Q fragments (issue loads first)
  bf16x8 qa[2];
  {
    const u16* qptr = Qh + ((rowbase + qbase + qloc) << 6);
    qa[0] = *(const bf16x8*)(qptr + (g << 3));
    qa[1] = *(const bf16x8*)(qptr + 32 + (g << 3));
  }

#define STAGE(buf, kt_) do { \
    const int k64_ = (kt_) << 6; \
    int L_ = (wid << 10) + lane * 16; \
    int row_ = L_ >> 7; \
    int off_ = (L_ & 127) ^ ((row_ & 7) << 4); \
    gload16((const char*)Kh + ((rowbase + k64_ + row_) << 7) + off_, (char*)Ks[buf] + (wid << 10)); \
    gload16((const char*)Vt + ((((size_t)bh << 6) + row_) << 11) + (k64_ << 1) + off_, (char*)Vs[buf] + (wid << 10)); \
  } while (0)

  STAGE(0, 0);

  // zero Pband (8192B), load rv32
  ((uint4*)Pband)[tid] = uint4{0, 0, 0, 0};
  if (tid < 64) rv32S[tid] = relv[2048 + tid];

  // qrel in prologue: qrelS[q][r] = (Q[q,:].relk[r,:]) * K1 - C0, via 6 MFMAs per wave
  {
    const f32x4 ZF = {0.f, 0.f, 0.f, 0.f};
#pragma unroll
    for (int t = 0; t < 3; ++t) {
      int rr = t * 16 + c; if (rr > 32) rr = 32;
      f32x4 qr = ZF;
#pragma unroll
      for (int kk = 0; kk < 2; ++kk) {
        bf16x8 ar = *(const bf16x8*)(relkb + (rr << 6) + (kk << 5) + (g << 3));
        qr = MFMA16(ar, qa[kk], qr);
      }
#pragma unroll
      for (int j = 0; j < 4; ++j) {
        int r = t * 16 + (g << 2) + j;
        if (r < 33) qrelS[qloc * 34 + r] = qr[j] * K1 - C0;
      }
    }
  }
  __syncthreads();   // covers STAGE(0), Pband init, qrelS, rv32S

  const float bias_lo = qrelS[qloc * 34 + 0];
  const float bias_hi = qrelS[qloc * 34 + 32];

  // hoisted loop-invariant LDS byte offsets
  int koff[4][2], voff[4][2], poffw[4];
#pragma unroll
  for (int t = 0; t < 4; ++t) {
#pragma unroll
    for (int kk = 0; kk < 2; ++kk)
      koff[t][kk] = ((t << 4) + c) * 128 + ((((kk << 6) | (g << 4))) ^ ((c & 7) << 4));
#pragma unroll
    for (int h2 = 0; h2 < 2; ++h2)
      voff[t][h2] = ((t << 4) + c) * 128 + ((((h2 << 6) | (g << 4))) ^ ((c & 7) << 4));
    poffw[t] = qloc * 128 + (((t << 5) | (g << 3)) ^ ((c & 7) << 4));
  }
  const int pr0 = qloc * 128 + ((g << 4) ^ ((c & 7) << 4));
  const int pr1 = pr0 ^ 64;

  const f32x4 ZF = {0.f, 0.f, 0.f, 0.f};
  f32x4 acc[4] = {ZF, ZF, ZF, ZF};
  float lsum = 0.f, lowsum = 0.f, psum = 0.f;

  for (int kt = 0; kt < 16; ++kt) {
    const int cur = kt & 1;
    if (kt < 15) STAGE(cur ^ 1, kt + 1);   // prefetch into other buffer

    // QK^T swapped: sa[t][j] = S[k = kt*64 + t*16 + g*4 + j][q = own]
    f32x4 sa[4];
#pragma unroll
    for (int t = 0; t < 4; ++t) {
      sa[t] = ZF;
#pragma unroll
      for (int kk = 0; kk < 2; ++kk) {
        bf16x8 bk = *(const bf16x8*)((const char*)Ks + (cur << 13) + koff[t][kk]);
        sa[t] = MFMA16(bk, qa[kk], sa[t]);
      }
    }

    const int D0 = (kt << 6) - qbase;
    float p[4][4];
    if (D0 >= 192) {            // all dlt >= 17: high bucket
      float s = 0.f;
#pragma unroll
      for (int t = 0; t < 4; ++t)
#pragma unroll
        for (int j = 0; j < 4; ++j) {
          float pe = __builtin_amdgcn_exp2f(fmaf(sa[t][j], K1, bias_hi));
          p[t][j] = pe; s += pe;
        }
      lsum += s;
    } else if (D0 <= -128) {    // all dlt <= -17: low bucket
      float s = 0.f;
#pragma unroll
      for (int t = 0; t < 4; ++t)
#pragma unroll
        for (int j = 0; j < 4; ++j) {
          float pe = __builtin_amdgcn_exp2f(fmaf(sa[t][j], K1, bias_lo));
          p[t][j] = pe; s += pe;
        }
      lsum += s; lowsum += s;
    } else {                    // boundary tiles (4 of 16)
#pragma unroll
      for (int t = 0; t < 4; ++t)
#pragma unroll
        for (int j = 0; j < 4; ++j) {
          int dlt = D0 + (t << 4) + (g << 2) + j - qloc;
          int idx = dlt < -16 ? 0 : (dlt > 16 ? 32 : dlt + 16);
          float pe = __builtin_amdgcn_exp2f(fmaf(sa[t][j], K1, qrelS[qloc * 34 + idx]));
          p[t][j] = pe;
          lsum += pe;
          if (dlt <= -16) lowsum += pe;
          else if (dlt < 16) { psum += pe; Pband[(qloc << 5) + dlt + 16] = f2bf(pe); }
        }
    }

    // P -> LDS (own row), then PV swapped: acc[dt][j] = O[d = dt*16+g*4+j][q = own]
#pragma unroll
    for (int t = 0; t < 4; ++t) {
      uint2 pk;
      pk.x = cvtpk(p[t][0], p[t][1]);
      pk.y = cvtpk(p[t][2], p[t][3]);
      *(uint2*)((char*)Ps + poffw[t]) = pk;
    }
    bf16x8 pb0 = *(const bf16x8*)((const char*)Ps + pr0);
    bf16x8 pb1 = *(const bf16x8*)((const char*)Ps + pr1);
#pragma unroll
    for (int dt = 0; dt < 4; ++dt) {
      bf16x8 av0 = *(const bf16x8*)((const char*)Vs + (cur << 13) + voff[dt][0]);
      bf16x8 av1 = *(const bf16x8*)((const char*)Vs + (cur << 13) + voff[dt][1]);
      acc[dt] = MFMA16(av0, pb0, acc[dt]);
      acc[dt] = MFMA16(av1, pb1, acc[dt]);
    }
    __syncthreads();   // drains prefetch + protects dbuf swap
  }

  // ---- epilogue ----
  lsum += __shfl_xor(lsum, 16);   lsum += __shfl_xor(lsum, 32);
  lowsum += __shfl_xor(lowsum, 16); lowsum += __shfl_xor(lowsum, 32);
  psum += __shfl_xor(psum, 16);   psum += __shfl_xor(psum, 32);
  const float inv = 1.f / lsum;
  const float hsum = lsum - lowsum - psum;   // unnormalized high-bucket mass

  if (g == 0) Pband[qloc << 5] = f2bf(lowsum);   // low bucket slot (unnormalized)

  // overlay rv^T (bf16 [d][r=0..31]) into dead qrelS
  u16* rvT = (u16*)qrelS;
  for (int i = tid; i < 4096; i += 512) rvT[i] = f2bf(relv[((i & 31) << 6) + (i >> 5)]);
  __syncthreads();

  // acc += rv^T[d][r] * Pband[r][q]  (band + low), all unnormalized
  bf16x8 pb2 = *(const bf16x8*)((const u16*)Pband + (qloc << 5) + (g << 3));
#pragma unroll
  for (int dt = 0; dt < 4; ++dt) {
    bf16x8 av = *(const bf16x8*)(rvT + (((dt << 4) + c) << 5) + (g << 3));
    acc[dt] = MFMA16(av, pb2, acc[dt]);
  }

  const int b = bh >> 3, h = bh & 7;
  const int q = qbase + qloc;
  u16* xb = Xout + ((((size_t)b << 10) + q) << 9) + (h << 6);
#pragma unroll
  for (int dt = 0; dt < 4; ++dt) {
    int d0 = (dt << 4) + (g << 2);
    float v0 = (acc[dt][0] + hsum * rv32S[d0 + 0]) * inv;
    float v1 = (acc[dt][1] + hsum * rv32S[d0 + 1]) * inv;
    float v2 = (acc[dt][2] + hsum * rv32S[d0 + 2]) * inv;
    float v3 = (acc[dt][3] + hsum * rv32S[d0 + 3]) * inv;
    uint2 o;
    o.x = cvtpk(v0, v1);
    o.y = cvtpk(v2, v3);
    *(uint2*)(xb + d0) = o;
  }
#undef STAGE
}

// ---------------- launch ----------------
extern "C" void kernel_launch(void* const* d_in, const int* in_sizes, int n_in,
                              void* d_out, int out_size, void* d_ws, size_t ws_size,
                              hipStream_t stream) {
  (void)in_sizes; (void)n_in; (void)out_size; (void)ws_size;
  const float* query = (const float*)d_in[0];
  const float* key   = (const float*)d_in[1];
  const float* value = (const float*)d_in[2];
  const float* Wq = (const float*)d_in[3];
  const float* bq = (const float*)d_in[4];
  const float* Wk = (const float*)d_in[5];
  const float* bk = (const float*)d_in[6];
  const float* Wv = (const float*)d_in[7];
  const float* bv = (const float*)d_in[8];
  const float* Wo = (const float*)d_in[9];
  const float* bo = (const float*)d_in[10];
  const float* relk = (const float*)d_in[11];
  const float* relv = (const float*)d_in[12];

  char* ws = (char*)d_ws;
  u16*   Xq    = (u16*)(ws + 0);
  u16*   Xk    = (u16*)(ws + 8388608);
  u16*   Xv    = (u16*)(ws + 16777216);
  u16*   Wqb   = (u16*)(ws + 25165824);
  u16*   Wkb   = (u16*)(ws + 25690112);
  u16*   Wvb   = (u16*)(ws + 26214400);
  u16*   Wob   = (u16*)(ws + 26738688);
  u16*   relkb = (u16*)(ws + 27262976);   // 33*64 bf16
  u16*   Qh    = (u16*)(ws + 27271168);
  u16*   Kh    = (u16*)(ws + 35659776);
  u16*   Vt    = (u16*)(ws + 52436992);
  u16*   Xout  = (u16*)(ws + 70262784);

  convAll<<<13315, 256, 0, stream>>>(query, key, value, Wq, Wk, Wv, Wo, relk,
                                     Xq, Xk, Xv, Wqb, Wkb, Wvb, Wob, relkb);
  qkv_gemm<<<768, 512, 0, stream>>>(Xq, Xk, Xv, Wqb, Wkb, Wvb, bq, bk, bv, Qh, Kh, Vt);
  flash_kernel<<<512, 512, 0, stream>>>(Qh, Kh, Vt, relkb, relv, Xout);
  gemm_out<<<256, 512, 0, stream>>>(Xout, Wob, bo, (float*)d_out);
}

// Round 17
// 85.325 us; speedup vs baseline: 1.1052x; 1.1052x over previous
//
#include <hip/hip_runtime.h>

typedef unsigned short u16;
typedef float f32x4 __attribute__((ext_vector_type(4)));
typedef __bf16 bf16x8 __attribute__((ext_vector_type(8)));

#define MFMA16(a, b, c) __builtin_amdgcn_mfma_f32_16x16x32_bf16((a), (b), (c), 0, 0, 0)

#define B_ 8
#define H_ 8
#define S_ 1024

__device__ __forceinline__ u16 f2bf(float f) {
  unsigned u = __float_as_uint(f);
  return (u16)((u + 0x7fffu + ((u >> 16) & 1u)) >> 16);
}
// pack 2 f32 -> 2 bf16 in one instr (dst.lo = a, dst.hi = b)
__device__ __forceinline__ unsigned cvtpk(float a, float b) {
  unsigned r;
  asm("v_cvt_pk_bf16_f32 %0, %1, %2" : "=v"(r) : "v"(a), "v"(b));
  return r;
}
// async global->LDS, 16B per lane. LDS dest = wave-uniform base + lane*16.
__device__ __forceinline__ void gload16(const void* g, void* l) {
  __builtin_amdgcn_global_load_lds((__attribute__((address_space(1))) const void*)g,
                                   (__attribute__((address_space(3))) void*)l, 16, 0, 0);
}

// ---------------- weights + relk fp32->bf16 (3.15 MB only) ----------------
__global__ void __launch_bounds__(256) convW(const float* __restrict__ s0, const float* __restrict__ s1,
                                             const float* __restrict__ s2, const float* __restrict__ s3,
                                             const float* __restrict__ s4,
                                             u16* __restrict__ d0, u16* __restrict__ d1, u16* __restrict__ d2,
                                             u16* __restrict__ d3, u16* __restrict__ d4) {
  size_t i = ((size_t)blockIdx.x * 256 + threadIdx.x) << 2;
  if (i >= 1050688) return; // 4*262144 + 33*64
  const float* s; u16* d; size_t off;
  if (i < 262144)       { s = s0; d = d0; off = i; }
  else if (i < 524288)  { s = s1; d = d1; off = i - 262144; }
  else if (i < 786432)  { s = s2; d = d2; off = i - 524288; }
  else if (i < 1048576) { s = s3; d = d3; off = i - 786432; }
  else                  { s = s4; d = d4; off = i - 1048576; }
  float4 f = *(const float4*)(s + off);
  uint2 o;
  o.x = cvtpk(f.x, f.y);
  o.y = cvtpk(f.z, f.w);
  *(uint2*)(d + off) = o;
}

// ---------------- fused Q/K/V projection GEMM: 768 blocks x 512 threads, BK=32, dbuf ----------------
// seg 0: Q -> bf16 head-split [B,H,S,64]; seg 1: K same; seg 2: V -> transposed [B*H,64,S].
// A staged as f32 via async gload16 (8-slot XOR swizzle, conflict-free). W (bf16, 64B rows) uses
// ROWPAIR swizzle: slot s = (row&1)*4+col16 stored at s^(rowpair&7) within each 128B line --
// removes the 4-way read conflict of the naive 4-slot layout (was 3.15M conflict cycles).
// XCD-chunked block swizzle keeps the 4 bn-blocks of one A row-block on the same XCD's L2.
__global__ void __launch_bounds__(512) qkv_gemm(const float* __restrict__ Aq, const float* __restrict__ Ak,
                                                const float* __restrict__ Av, const u16* __restrict__ Wqb,
                                                const u16* __restrict__ Wkb, const u16* __restrict__ Wvb,
                                                const float* __restrict__ bq, const float* __restrict__ bk,
                                                const float* __restrict__ bv, u16* __restrict__ Qh,
                                                u16* __restrict__ Kh, u16* __restrict__ Vt) {
  __shared__ float Asf[2][128 * 32];   // 2 x 16 KB f32 A tiles (128B rows, 8-slot swizzle)
  __shared__ u16 Bs[2][128 * 32];      // 2 x 8 KB bf16 W tiles (rowpair swizzle)
  // 768 blocks, 8 XCDs, 96 per XCD (exact): XCD x gets logical work [96x, 96x+96)
  const int w = (blockIdx.x & 7) * 96 + (blockIdx.x >> 3);
  const int seg = w >> 8, bid = w & 255;
  const float* Af = seg == 0 ? Aq : (seg == 1 ? Ak : Av);
  const u16* W = seg == 0 ? Wqb : (seg == 1 ? Wkb : Wvb);
  const float* bias = seg == 0 ? bq : (seg == 1 ? bk : bv);
  const int tid = threadIdx.x, lane = tid & 63, wid = tid >> 6;   // wid 0..7
  const int c = lane & 15, g = lane >> 4;
  const int bm = bid >> 2, bn = bid & 3;
  const int m0 = bm << 7, n0 = bn << 7;
  const int wrow = (wid & 3) << 5;    // 0/32/64/96
  const int wcol = (wid >> 2) << 6;   // 0/64

  // stage k-tile (32 elems) into buffer buf: A = 2 gloads/thread (f32), W = 1 gload/thread (bf16)
#define STAGEQ(buf, kt_) do { \
    _Pragma("unroll") \
    for (int j_ = 0; j_ < 2; ++j_) { \
      int s0_ = ((wid << 1) | j_) << 6; \
      int s_ = s0_ + lane; \
      int row_ = s_ >> 3; \
      int sl_ = (s_ & 7) ^ (row_ & 7); \
      gload16((const char*)Af + ((((size_t)(m0 + row_)) << 9) + (kt_)) * 4 + (sl_ << 4), \
              (char*)Asf[buf] + (s0_ << 4)); \
    } \
    { \
      int G_ = (wid << 6) + lane; \
      int P_ = G_ >> 3; \
      int si_ = (G_ & 7) ^ (P_ & 7); \
      int row_ = (P_ << 1) | (si_ >> 2); \
      gload16((const char*)W + ((((size_t)(n0 + row_)) << 9) + (kt_)) * 2 + ((si_ & 3) << 4), \
              (char*)Bs[buf] + (G_ << 4)); \
    } \
  } while (0)

  const f32x4 ZF = {0.f, 0.f, 0.f, 0.f};
  f32x4 acc[2][4];
#pragma unroll
  for (int i = 0; i < 2; ++i)
#pragma unroll
    for (int j = 0; j < 4; ++j) acc[i][j] = ZF;

  STAGEQ(0, 0);
  __syncthreads();   // drain prologue stage

  for (int it = 0; it < 16; ++it) {
    const int cur = it & 1;
    if (it < 15) STAGEQ(cur ^ 1, (it + 1) << 5);   // prefetch next tile, hides under compute

    bf16x8 af[2], bfr[4];
#pragma unroll
    for (int rt = 0; rt < 2; ++rt) {
      int row = wrow + (rt << 4) + c;
      const char* pA = (const char*)Asf[cur] + row * 128;
      int sw = row & 7;
      float4 f0 = *(const float4*)(pA + ((((g << 1) | 0) ^ sw) << 4));
      float4 f1 = *(const float4*)(pA + ((((g << 1) | 1) ^ sw) << 4));
      uint4 aw;
      aw.x = cvtpk(f0.x, f0.y); aw.y = cvtpk(f0.z, f0.w);
      aw.z = cvtpk(f1.x, f1.y); aw.w = cvtpk(f1.z, f1.w);
      af[rt] = __builtin_bit_cast(bf16x8, aw);
    }
#pragma unroll
    for (int ct = 0; ct < 4; ++ct) {
      int row = wcol + (ct << 4) + c;
      int P = row >> 1;
      int sp = (((row & 1) << 2) | g) ^ (P & 7);
      bfr[ct] = *(const bf16x8*)((const char*)Bs[cur] + (P << 7) + (sp << 4));
    }
#pragma unroll
    for (int rt = 0; rt < 2; ++rt)
#pragma unroll
      for (int ct = 0; ct < 4; ++ct) acc[rt][ct] = MFMA16(af[rt], bfr[ct], acc[rt][ct]);

    if (it < 15) __syncthreads();   // drains prefetch + gates buffer swap
  }

#pragma unroll
  for (int rt = 0; rt < 2; ++rt)
#pragma unroll
    for (int ct = 0; ct < 4; ++ct) {
      int n = n0 + wcol + (ct << 4) + c;
      float bv2 = bias[n];
      if (seg == 2) {
        int b2 = m0 >> 10;
        int sbase = (m0 & 1023) + wrow + (rt << 4) + (g << 2);
        int h2 = n >> 6, d2 = n & 63;
        uint2 o;
        o.x = cvtpk(acc[rt][ct][0] + bv2, acc[rt][ct][1] + bv2);
        o.y = cvtpk(acc[rt][ct][2] + bv2, acc[rt][ct][3] + bv2);
        *(uint2*)(Vt + ((((size_t)((b2 << 3) + h2) << 6) + d2) << 10) + sbase) = o;
      } else {
        u16* out = seg == 0 ? Qh : Kh;
#pragma unroll
        for (int r = 0; r < 4; ++r) {
          int m = m0 + wrow + (rt << 4) + (g << 2) + r;
          int b = m >> 10, s = m & 1023, h = n >> 6, d = n & 63;
          out[(((((size_t)(b * H_ + h)) << 10) + s) << 6) + d] = f2bf(acc[rt][ct][r] + bv2);
        }
      }
    }
#undef STAGEQ
}

// ---------------- output GEMM: 256 blocks x 512 threads, BK=32, dbuf, rowpair-swizzled tiles ----------------
__global__ void __launch_bounds__(512) gemm_out(const u16* __restrict__ A, const u16* __restrict__ W,
                                                const float* __restrict__ bias, float* __restrict__ out) {
  __shared__ u16 As2[2][128 * 32];   // 2 x 8 KB (rowpair swizzle)
  __shared__ u16 Bs2[2][128 * 32];   // 2 x 8 KB (rowpair swizzle)
  // XCD swizzle: 256 blocks, 32 per XCD (exact)
  const int wb = (blockIdx.x & 7) * 32 + (blockIdx.x >> 3);
  const int tid = threadIdx.x, lane = tid & 63, wid = tid >> 6;
  const int c = lane & 15, g = lane >> 4;
  const int bm = wb >> 2, bn = wb & 3;
  const int m0 = bm << 7, n0 = bn << 7;
  const int wrow = (wid & 3) << 5;    // 0/32/64/96
  const int wcol = (wid >> 2) << 6;   // 0/64

#define STAGEO(buf, kt_) do { \
    int G_ = (wid << 6) + lane; \
    int P_ = G_ >> 3; \
    int si_ = (G_ & 7) ^ (P_ & 7); \
    int row_ = (P_ << 1) | (si_ >> 2); \
    int col_ = (si_ & 3) << 4; \
    gload16((const char*)A + ((((size_t)(m0 + row_)) << 9) + (kt_)) * 2 + col_, \
            (char*)As2[buf] + (G_ << 4)); \
    gload16((const char*)W + ((((size_t)(n0 + row_)) << 9) + (kt_)) * 2 + col_, \
            (char*)Bs2[buf] + (G_ << 4)); \
  } while (0)

  const f32x4 ZF = {0.f, 0.f, 0.f, 0.f};
  f32x4 acc[2][4];
#pragma unroll
  for (int i = 0; i < 2; ++i)
#pragma unroll
    for (int j = 0; j < 4; ++j) acc[i][j] = ZF;

  STAGEO(0, 0);
  __syncthreads();

  for (int it = 0; it < 16; ++it) {
    const int cur = it & 1;
    if (it < 15) STAGEO(cur ^ 1, (it + 1) << 5);

    bf16x8 af[2], bfr[4];
#pragma unroll
    for (int rt = 0; rt < 2; ++rt) {
      int row = wrow + (rt << 4) + c;
      int P = row >> 1;
      int sp = (((row & 1) << 2) | g) ^ (P & 7);
      af[rt] = *(const bf16x8*)((const char*)As2[cur] + (P << 7) + (sp << 4));
    }
#pragma unroll
    for (int ct = 0; ct < 4; ++ct) {
      int row = wcol + (ct << 4) + c;
      int P = row >> 1;
      int sp = (((row & 1) << 2) | g) ^ (P & 7);
      bfr[ct] = *(const bf16x8*)((const char*)Bs2[cur] + (P << 7) + (sp << 4));
    }
#pragma unroll
    for (int rt = 0; rt < 2; ++rt)
#pragma unroll
      for (int ct = 0; ct < 4; ++ct) acc[rt][ct] = MFMA16(af[rt], bfr[ct], acc[rt][ct]);

    if (it < 15) __syncthreads();
  }

#pragma unroll
  for (int rt = 0; rt < 2; ++rt)
#pragma unroll
    for (int ct = 0; ct < 4; ++ct) {
      int n = n0 + wcol + (ct << 4) + c;
      float bv = bias[n];
#pragma unroll
      for (int r = 0; r < 4; ++r) {
        int m = m0 + wrow + (rt << 4) + (g << 2) + r;
        out[(((size_t)m) << 9) + n] = acc[rt][ct][r] + bv;
      }
    }
#undef STAGEO
}

// ---------------- flash attention: round-4 structure (8 waves, 128 q, fused qrel + rel-V) ----------------
// lane (c,g) of wave wid owns q = qbase + wid*16 + c everywhere.
__global__ void __launch_bounds__(512) flash_kernel(const u16* __restrict__ Qh, const u16* __restrict__ Kh,
                                                    const u16* __restrict__ Vt, const u16* __restrict__ relkb,
                                                    const float* __restrict__ relv, u16* __restrict__ Xout) {
  __shared__ u16 Ks[2][64 * 64];
  __shared__ u16 Vs[2][64 * 64];
  __shared__ u16 Ps[128 * 64];
  __shared__ float qrelS[128 * 34];   // exp2-domain bias table; overlaid by rvT in epilogue
  __shared__ u16 Pband[128 * 32];     // unnormalized bf16 band probs; slot 0 = low bucket
  __shared__ float rv32S[64];

  const int tid = threadIdx.x, lane = tid & 63, wid = tid >> 6;
  const int c = lane & 15, g = lane >> 4;
  // XCD swizzle: 8 chunks of 64 consecutive blocks
  const int swz = ((blockIdx.x & 7) << 6) | (blockIdx.x >> 3);
  const int bh = swz >> 3, qt = swz & 7;
  const int qbase = qt << 7;
  const size_t rowbase = ((size_t)bh) << 10;
  const int qloc = (wid << 4) + c;
  const float K1 = 0.51013619f;   // (1/sqrt(8)) * log2(e)
  const float C0 = 24.0f;

  // Q fragments (issue loads first)
  bf16x8 qa[2];
  {
    const u16* qptr = Qh + ((rowbase + qbase + qloc) << 6);
    qa[0] = *(const bf16x8*)(qptr + (g << 3));
    qa[1] = *(const bf16x8*)(qptr + 32 + (g << 3));
  }

#define STAGE(buf, kt_) do { \
    const int k64_ = (kt_) << 6; \
    int L_ = (wid << 10) + lane * 16; \
    int row_ = L_ >> 7; \
    int off_ = (L_ & 127) ^ ((row_ & 7) << 4); \
    gload16((const char*)Kh + ((rowbase + k64_ + row_) << 7) + off_, (char*)Ks[buf] + (wid << 10)); \
    gload16((const char*)Vt + ((((size_t)bh << 6) + row_) << 11) + (k64_ << 1) + off_, (char*)Vs[buf] + (wid << 10)); \
  } while (0)

  STAGE(0, 0);

  // zero Pband (8192B), load rv32
  ((uint4*)Pband)[tid] = uint4{0, 0, 0, 0};
  if (tid < 64) rv32S[tid] = relv[2048 + tid];

  // qrel in prologue: qrelS[q][r] = (Q[q,:].relk[r,:]) * K1 - C0, via 6 MFMAs per wave
  {
    const f32x4 ZF = {0.f, 0.f, 0.f, 0.f};
#pragma unroll
    for (int t = 0; t < 3; ++t) {
      int rr = t * 16 + c; if (rr > 32) rr = 32;
      f32x4 qr = ZF;
#pragma unroll
      for (int kk = 0; kk < 2; ++kk) {
        bf16x8 ar = *(const bf16x8*)(relkb + (rr << 6) + (kk << 5) + (g << 3));
        qr = MFMA16(ar, qa[kk], qr);
      }
#pragma unroll
      for (int j = 0; j < 4; ++j) {
        int r = t * 16 + (g << 2) + j;
        if (r < 33) qrelS[qloc * 34 + r] = qr[j] * K1 - C0;
      }
    }
  }
  __syncthreads();   // covers STAGE(0), Pband init, qrelS, rv32S

  const float bias_lo = qrelS[qloc * 34 + 0];
  const float bias_hi = qrelS[qloc * 34 + 32];

  // hoisted loop-invariant LDS byte offsets
  int koff[4][2], voff[4][2], poffw[4];
#pragma unroll
  for (int t = 0; t < 4; ++t) {
#pragma unroll
    for (int kk = 0; kk < 2; ++kk)
      koff[t][kk] = ((t << 4) + c) * 128 + ((((kk << 6) | (g << 4))) ^ ((c & 7) << 4));
#pragma unroll
    for (int h2 = 0; h2 < 2; ++h2)
      voff[t][h2] = ((t << 4) + c) * 128 + ((((h2 << 6) | (g << 4))) ^ ((c & 7) << 4));
    poffw[t] = qloc * 128 + (((t << 5) | (g << 3)) ^ ((c & 7) << 4));
  }
  const int pr0 = qloc * 128 + ((g << 4) ^ ((c & 7) << 4));
  const int pr1 = pr0 ^ 64;

  const f32x4 ZF = {0.f, 0.f, 0.f, 0.f};
  f32x4 acc[4] = {ZF, ZF, ZF, ZF};
  float lsum = 0.f, lowsum = 0.f, psum = 0.f;

  for (int kt = 0; kt < 16; ++kt) {
    const int cur = kt & 1;
    if (kt < 15) STAGE(cur ^ 1, kt + 1);   // prefetch into other buffer

    // QK^T swapped: sa[t][j] = S[k = kt*64 + t*16 + g*4 + j][q = own]
    f32x4 sa[4];
#pragma unroll
    for (int t = 0; t < 4; ++t) {
      sa[t] = ZF;
#pragma unroll
      for (int kk = 0; kk < 2; ++kk) {
        bf16x8 bk = *(const bf16x8*)((const char*)Ks + (cur << 13) + koff[t][kk]);
        sa[t] = MFMA16(bk, qa[kk], sa[t]);
      }
    }

    const int D0 = (kt << 6) - qbase;
    float p[4][4];
    if (D0 >= 192) {            // all dlt >= 17: high bucket
      float s = 0.f;
#pragma unroll
      for (int t = 0; t < 4; ++t)
#pragma unroll
        for (int j = 0; j < 4; ++j) {
          float pe = __builtin_amdgcn_exp2f(fmaf(sa[t][j], K1, bias_hi));
          p[t][j] = pe; s += pe;
        }
      lsum += s;
    } else if (D0 <= -128) {    // all dlt <= -17: low bucket
      float s = 0.f;
#pragma unroll
      for (int t = 0; t < 4; ++t)
#pragma unroll
        for (int j = 0; j < 4; ++j) {
          float pe = __builtin_amdgcn_exp2f(fmaf(sa[t][j], K1, bias_lo));
          p[t][j] = pe; s += pe;
        }
      lsum += s; lowsum += s;
    } else {                    // boundary tiles (4 of 16)
#pragma unroll
      for (int t = 0; t < 4; ++t)
#pragma unroll
        for (int j = 0; j < 4; ++j) {
          int dlt = D0 + (t << 4) + (g << 2) + j - qloc;
          int idx = dlt < -16 ? 0 : (dlt > 16 ? 32 : dlt + 16);
          float pe = __builtin_amdgcn_exp2f(fmaf(sa[t][j], K1, qrelS[qloc * 34 + idx]));
          p[t][j] = pe;
          lsum += pe;
          if (dlt <= -16) lowsum += pe;
          else if (dlt < 16) { psum += pe; Pband[(qloc << 5) + dlt + 16] = f2bf(pe); }
        }
    }

    // P -> LDS (own row), then PV swapped: acc[dt][j] = O[d = dt*16+g*4+j][q = own]
#pragma unroll
    for (int t = 0; t < 4; ++t) {
      uint2 pk;
      pk.x = cvtpk(p[t][0], p[t][1]);
      pk.y = cvtpk(p[t][2], p[t][3]);
      *(uint2*)((char*)Ps + poffw[t]) = pk;
    }
    bf16x8 pb0 = *(const bf16x8*)((const char*)Ps + pr0);
    bf16x8 pb1 = *(const bf16x8*)((const char*)Ps + pr1);
#pragma unroll
    for (int dt = 0; dt < 4; ++dt) {
      bf16x8 av0 = *(const bf16x8*)((const char*)Vs + (cur << 13) + voff[dt][0]);
      bf16x8 av1 = *(const bf16x8*)((const char*)Vs + (cur << 13) + voff[dt][1]);
      acc[dt] = MFMA16(av0, pb0, acc[dt]);
      acc[dt] = MFMA16(av1, pb1, acc[dt]);
    }
    __syncthreads();   // drains prefetch + protects dbuf swap
  }

  // ---- epilogue ----
  lsum += __shfl_xor(lsum, 16);   lsum += __shfl_xor(lsum, 32);
  lowsum += __shfl_xor(lowsum, 16); lowsum += __shfl_xor(lowsum, 32);
  psum += __shfl_xor(psum, 16);   psum += __shfl_xor(psum, 32);
  const float inv = 1.f / lsum;
  const float hsum = lsum - lowsum - psum;   // unnormalized high-bucket mass

  if (g == 0) Pband[qloc << 5] = f2bf(lowsum);   // low bucket slot (unnormalized)

  // overlay rv^T (bf16 [d][r=0..31]) into dead qrelS
  u16* rvT = (u16*)qrelS;
  for (int i = tid; i < 4096; i += 512) rvT[i] = f2bf(relv[((i & 31) << 6) + (i >> 5)]);
  __syncthreads();

  // acc += rv^T[d][r] * Pband[r][q]  (band + low), all unnormalized
  bf16x8 pb2 = *(const bf16x8*)((const u16*)Pband + (qloc << 5) + (g << 3));
#pragma unroll
  for (int dt = 0; dt < 4; ++dt) {
    bf16x8 av = *(const bf16x8*)(rvT + (((dt << 4) + c) << 5) + (g << 3));
    acc[dt] = MFMA16(av, pb2, acc[dt]);
  }

  const int b = bh >> 3, h = bh & 7;
  const int q = qbase + qloc;
  u16* xb = Xout + ((((size_t)b << 10) + q) << 9) + (h << 6);
#pragma unroll
  for (int dt = 0; dt < 4; ++dt) {
    int d0 = (dt << 4) + (g << 2);
    float v0 = (acc[dt][0] + hsum * rv32S[d0 + 0]) * inv;
    float v1 = (acc[dt][1] + hsum * rv32S[d0 + 1]) * inv;
    float v2 = (acc[dt][2] + hsum * rv32S[d0 + 2]) * inv;
    float v3 = (acc[dt][3] + hsum * rv32S[d0 + 3]) * inv;
    uint2 o;
    o.x = cvtpk(v0, v1);
    o.y = cvtpk(v2, v3);
    *(uint2*)(xb + d0) = o;
  }
#undef STAGE
}

// ---------------- launch ----------------
extern "C" void kernel_launch(void* const* d_in, const int* in_sizes, int n_in,
                              void* d_out, int out_size, void* d_ws, size_t ws_size,
                              hipStream_t stream) {
  (void)in_sizes; (void)n_in; (void)out_size; (void)ws_size;
  const float* query = (const float*)d_in[0];
  const float* key   = (const float*)d_in[1];
  const float* value = (const float*)d_in[2];
  const float* Wq = (const float*)d_in[3];
  const float* bq = (const float*)d_in[4];
  const float* Wk = (const float*)d_in[5];
  const float* bk = (const float*)d_in[6];
  const float* Wv = (const float*)d_in[7];
  const float* bv = (const float*)d_in[8];
  const float* Wo = (const float*)d_in[9];
  const float* bo = (const float*)d_in[10];
  const float* relk = (const float*)d_in[11];
  const float* relv = (const float*)d_in[12];

  char* ws = (char*)d_ws;
  u16*   Wqb   = (u16*)(ws + 25165824);
  u16*   Wkb   = (u16*)(ws + 25690112);
  u16*   Wvb   = (u16*)(ws + 26214400);
  u16*   Wob   = (u16*)(ws + 26738688);
  u16*   relkb = (u16*)(ws + 27262976);   // 33*64 bf16
  u16*   Qh    = (u16*)(ws + 27271168);
  u16*   Kh    = (u16*)(ws + 35659776);
  u16*   Vt    = (u16*)(ws + 52436992);
  u16*   Xout  = (u16*)(ws + 70262784);

  convW<<<1027, 256, 0, stream>>>(Wq, Wk, Wv, Wo, relk, Wqb, Wkb, Wvb, Wob, relkb);
  qkv_gemm<<<768, 512, 0, stream>>>(query, key, value, Wqb, Wkb, Wvb, bq, bk, bv, Qh, Kh, Vt);
  flash_kernel<<<512, 512, 0, stream>>>(Qh, Kh, Vt, relkb, relv, Xout);
  gemm_out<<<256, 512, 0, stream>>>(Xout, Wob, bo, (float*)d_out);
}